// Round 13
// baseline (226.604 us; speedup 1.0000x reference)
//
#include <hip/hip_runtime.h>
#include <hip/hip_bf16.h>

#define NN 4096
#define FIN 128
#define FOUT 64
#define NH 8
#define KS 4          // K splits (1024 keys per block)
#define QT 32         // Q rows per block

typedef float f32x4 __attribute__((ext_vector_type(4)));
typedef __bf16 bf16x8 __attribute__((ext_vector_type(8)));
typedef unsigned long long u64;

// ---------------- K0: fused prep.
// Blocks 0..127: per-block 32 x-rows: build Wc in LDS (redundantly, L2-hot),
//   compute skipm (to d_out) + EF + C12, convert x->bf16 into LDS, then per-head
//   proj staging + MFMA to produce Vt[h][f][n]. No xb global round-trip.
// Blocks 128..2175: topology -> bitmask streaming build.
__global__ __launch_bounds__(256) void prep_kernel(
    const float* __restrict__ x, const float* __restrict__ topo,
    const float* __restrict__ proj, const float* __restrict__ score_src,
    const float* __restrict__ score_dst, const float* __restrict__ skip_w,
    float* __restrict__ skipm, unsigned* __restrict__ EF, float2* __restrict__ C12,
    __hip_bfloat16* __restrict__ Vt_, u64* __restrict__ mb) {
    const int tid = threadIdx.x;

    if (blockIdx.x >= 128) {           // ---- mask role
        const int w = (blockIdx.x - 128) * 4 + (tid >> 6);
        const int lane = tid & 63;
        size_t base = (size_t)w * 32;
#pragma unroll 4
        for (int it = 0; it < 32; ++it) {
            size_t u = base + it;
            float t = topo[u * 64 + lane];
            u64 b = __ballot(t > -0.5e9f);
            if (lane == 0) mb[u] = b;
        }
        return;
    }

    // ---- prep role
    __shared__ float xs[32][FIN + 5];              // 17 KB
    __shared__ __align__(16) char ubuf[40960];     // wcs fp32 [128][80]  OR  xbs+pTs
    float* wcs = (float*)ubuf;
    const int n0 = blockIdx.x * 32;

    // stage x tile (32 x 128 fp32)
    const float4* xsrc = (const float4*)(x + (size_t)n0 * FIN);
    for (int i = tid; i < 32 * FIN / 4; i += 256) {
        int r = i >> 5, c4 = i & 31;
        *(float4*)&xs[r][c4 * 4] = xsrc[i];
    }
    // build Wc: score cols 0..15 = proj[h] @ score_{src,dst}[h]
    for (int t = tid; t < 2048; t += 256) {
        int i = t >> 4, c = t & 15, h = c & 7;
        const float* wv = (c < 8 ? score_src : score_dst) + h * FOUT;
        const float* p = proj + (size_t)h * FIN * FOUT + (size_t)i * FOUT;
        float v = 0.f;
#pragma unroll 8
        for (int f = 0; f < FOUT; ++f) v += p[f] * wv[f];
        wcs[i * 80 + c] = v;
    }
    // skip cols 16..79 = head-folded skip_w / 8
    for (int t = tid; t < 8192; t += 256) {
        int i = t >> 6, f = t & 63;
        float v = 0.f;
#pragma unroll
        for (int h = 0; h < NH; ++h) v += skip_w[(size_t)(h * FOUT + f) * FIN + i];
        wcs[i * 80 + 16 + f] = 0.125f * v;
    }
    __syncthreads();

    // scores + skipm: 8 groups x 32 rows; group g: skip cols g*8..g*8+7, score cols g*2,g*2+1
    {
        const int r = tid & 31, g = tid >> 5;
        float acc[8];
        float sa0 = 0.f, sa1 = 0.f;
#pragma unroll
        for (int j = 0; j < 8; ++j) acc[j] = 0.f;
#pragma unroll 4
        for (int i = 0; i < FIN; ++i) {
            float xv = xs[r][i];
            const float* wr = &wcs[i * 80];
            float4 p0 = *(float4*)(wr + 16 + g * 8);
            float4 p1 = *(float4*)(wr + 16 + g * 8 + 4);
            float2 q0 = *(float2*)(wr + g * 2);
            acc[0] += xv * p0.x; acc[1] += xv * p0.y; acc[2] += xv * p0.z; acc[3] += xv * p0.w;
            acc[4] += xv * p1.x; acc[5] += xv * p1.y; acc[6] += xv * p1.z; acc[7] += xv * p1.w;
            sa0 += xv * q0.x; sa1 += xv * q0.y;
        }
        int n = n0 + r;
#pragma unroll
        for (int j = 0; j < 8; ++j) skipm[(size_t)n * FOUT + g * 8 + j] = acc[j];
        int c0 = g * 2;
        if (c0 < 8) {
            C12[c0 * NN + n] = make_float2(expf(sa0), expf(0.2f * sa0));
            C12[(c0 + 1) * NN + n] = make_float2(expf(sa1), expf(0.2f * sa1));
        } else {
            __hip_bfloat16 e0 = __float2bfloat16(expf(sa0));
            __hip_bfloat16 f0 = __float2bfloat16(expf(0.2f * sa0));
            __hip_bfloat16 e1 = __float2bfloat16(expf(sa1));
            __hip_bfloat16 f1 = __float2bfloat16(expf(0.2f * sa1));
            EF[(c0 - 8) * NN + n] = ((unsigned)*(unsigned short*)&f0 << 16) | (unsigned)*(unsigned short*)&e0;
            EF[(c0 - 7) * NN + n] = ((unsigned)*(unsigned short*)&f1 << 16) | (unsigned)*(unsigned short*)&e1;
        }
    }
    __syncthreads();   // all wcs reads done; ubuf reusable

    // x -> bf16 into LDS (xbs), stage pT for head 0
    __bf16 (*xbs)[136] = (__bf16 (*)[136])ubuf;                 // 8.7 KB
    __bf16 (*pTs)[136] = (__bf16 (*)[136])(ubuf + 8704);        // 17.4 KB
    {
        int row = tid >> 3, col0 = (tid & 7) * 16;
        const float* src = &xs[row][col0];
        bf16x8 b0, b1;
#pragma unroll
        for (int j = 0; j < 8; ++j) { b0[j] = (__bf16)src[j]; b1[j] = (__bf16)src[8 + j]; }
        *(bf16x8*)&xbs[row][col0] = b0;
        *(bf16x8*)&xbs[row][col0 + 8] = b1;
    }
    for (int idx = tid; idx < FIN * FOUT; idx += 256) {
        int i = idx >> 6, f = idx & 63;
        pTs[f][i] = (__bf16)proj[idx];                           // head 0
    }
    __syncthreads();

    // per-head Vt MFMA: wave w owns f-tile w*16..w*16+15, both row-tiles
    const int lane = tid & 63, q = lane >> 4, li = lane & 15, w = tid >> 6;
    __bf16* Vt = (__bf16*)Vt_;
#pragma unroll 1
    for (int h = 0; h < NH; ++h) {
#pragma unroll
        for (int rt = 0; rt < 2; ++rt) {
            f32x4 va = (f32x4){0.f, 0.f, 0.f, 0.f};
#pragma unroll
            for (int kt = 0; kt < 4; ++kt) {
                bf16x8 bfrag = *(const bf16x8*)&xbs[rt * 16 + li][kt * 32 + q * 8];
                bf16x8 afrag = *(const bf16x8*)&pTs[w * 16 + li][kt * 32 + q * 8];
                va = __builtin_amdgcn_mfma_f32_16x16x32_bf16(afrag, bfrag, va, 0, 0, 0);
            }
#pragma unroll
            for (int reg = 0; reg < 4; ++reg)
                Vt[((size_t)h * FOUT + w * 16 + q * 4 + reg) * NN + n0 + rt * 16 + li] =
                    (__bf16)va[reg];
        }
        __syncthreads();
        if (h < 7) {
            const float* ph = proj + (size_t)(h + 1) * FIN * FOUT;
            for (int idx = tid; idx < FIN * FOUT; idx += 256) {
                int i = idx >> 6, f = idx & 63;
                pTs[f][i] = (__bf16)ph[idx];
            }
            __syncthreads();
        }
    }
}

// ---------------- K1: attention (R12, unchanged): head-per-wave, wave-private
// LDS-DMA double buffer, MFMA row-sums. grid = 128 qt x 4 ks x 2 hb = 1024 x 256.
__attribute__((amdgpu_waves_per_eu(4)))
__global__ __launch_bounds__(256) void attn_kernel(
    const u64* __restrict__ maskbits, const __hip_bfloat16* __restrict__ Vt_,
    const unsigned* __restrict__ EFg, const float2* __restrict__ C12g,
    __hip_bfloat16* __restrict__ accP, float* __restrict__ rsP) {
    __shared__ u64 maskS[QT][17];         // 4.4 KB
    __shared__ char vA[4][4096];          // 16 KB: per-wave buffer A
    __shared__ char vB[4][4096];          // 16 KB: per-wave buffer B
    const int tid = threadIdx.x;
    const int w = tid >> 6;
    const int lane = tid & 63, q = lane >> 4, li = lane & 15;
    const int qt = blockIdx.x >> 3, ks = (blockIdx.x >> 1) & 3, hb = blockIdx.x & 1;
    const int h = hb * 4 + w;
    const int row0 = qt * QT;
    const int kb0 = ks * 1024;

    const int r_ = lane >> 2;
    const int sg = ((lane & 3) - (r_ >> 1)) & 3;
    const size_t laneoff = (size_t)r_ * NN + sg * 8;            // bf16 units
    const int rdoff = li * 64 + ((q + (li >> 1)) & 3) * 16;     // bytes

    const __bf16* vb = (const __bf16*)Vt_ + (size_t)h * (FOUT * NN) + kb0;
    const unsigned* efb = EFg + (size_t)h * NN + kb0;

#define DMA_TILE(DST, KT) do {                                                     \
    _Pragma("unroll")                                                              \
    for (int c = 0; c < 4; ++c) {                                                  \
        const __bf16* g_ = vb + (size_t)c * (16 * NN) + (KT) * 32 + laneoff;       \
        __builtin_amdgcn_global_load_lds(                                          \
            (const __attribute__((address_space(1))) void*)g_,                     \
            (__attribute__((address_space(3))) void*)&DST[w][c * 1024], 16, 0, 0); \
    }                                                                              \
} while (0)

    DMA_TILE(vA, 0);
    {   // stage 32 rows x 16 mask words (512 words, 2 per thread)
        int i0 = tid, i1 = tid + 256;
        maskS[i0 >> 4][i0 & 15] = maskbits[(size_t)(row0 + (i0 >> 4)) * 64 + ks * 16 + (i0 & 15)];
        maskS[i1 >> 4][i1 & 15] = maskbits[(size_t)(row0 + (i1 >> 4)) * 64 + ks * 16 + (i1 & 15)];
    }
    __syncthreads();                      // also drains DMA(0)

    float C1[2], C2[2];
#pragma unroll
    for (int rt = 0; rt < 2; ++rt) {
        float2 c = C12g[(size_t)h * NN + row0 + rt * 16 + li];
        C1[rt] = c.x; C2[rt] = c.y;
    }
    bf16x8 ones;
#pragma unroll
    for (int j = 0; j < 8; ++j) ones[j] = (__bf16)1.0f;

    f32x4 acc[2][4];
    f32x4 rsacc[2];
#pragma unroll
    for (int rt = 0; rt < 2; ++rt) {
#pragma unroll
        for (int n = 0; n < 4; ++n) acc[rt][n] = (f32x4){0.f, 0.f, 0.f, 0.f};
        rsacc[rt] = (f32x4){0.f, 0.f, 0.f, 0.f};
    }

#define CHUNK_BODY(SRC, DSTN, KT) do {                                                        \
    const unsigned* ep_ = efb + (KT) * 32 + q * 8;                                            \
    uint4 ea_ = *(const uint4*)ep_;                                                           \
    uint4 eb_ = *(const uint4*)(ep_ + 4);                                                     \
    asm volatile("" ::: "memory");             /* pin EF loads before the DMA */              \
    DMA_TILE(DSTN, ((KT) + 1) & 31);                                                          \
    asm volatile("s_waitcnt vmcnt(4)" ::: "memory");                                          \
    bf16x8 vf_[4];                                                                            \
    _Pragma("unroll")                                                                         \
    for (int n = 0; n < 4; ++n)                                                               \
        vf_[n] = *(const bf16x8*)&SRC[w][n * 1024 + rdoff];                                   \
    unsigned ew_[8] = {ea_.x, ea_.y, ea_.z, ea_.w, eb_.x, eb_.y, eb_.z, eb_.w};               \
    _Pragma("unroll")                                                                         \
    for (int rt = 0; rt < 2; ++rt) {                                                          \
        u64 mw_ = maskS[rt * 16 + li][(KT) >> 1];                                             \
        unsigned mm_ = (unsigned)(mw_ >> (((KT) & 1) * 32 + q * 8)) & 0xffu;                  \
        bf16x8 pf_;                                                                           \
        _Pragma("unroll")                                                                     \
        for (int j = 0; j < 8; ++j) {                                                         \
            unsigned e_ = ew_[j];                                                             \
            float E_ = __uint_as_float(e_ << 16);                                             \
            float F_ = __uint_as_float(e_ & 0xffff0000u);                                     \
            float pv_ = fmaxf(C1[rt] * E_, C2[rt] * F_);                                      \
            pv_ = ((mm_ >> j) & 1u) ? pv_ : 0.f;                                              \
            pf_[j] = (__bf16)pv_;                                                             \
        }                                                                                     \
        rsacc[rt] = __builtin_amdgcn_mfma_f32_16x16x32_bf16(pf_, ones, rsacc[rt], 0, 0, 0);   \
        _Pragma("unroll")                                                                     \
        for (int n = 0; n < 4; ++n)                                                           \
            acc[rt][n] = __builtin_amdgcn_mfma_f32_16x16x32_bf16(pf_, vf_[n], acc[rt][n],     \
                                                                 0, 0, 0);                    \
    }                                                                                         \
} while (0)

#pragma unroll 1
    for (int kt = 0; kt < 32; kt += 2) {
        CHUNK_BODY(vA, vB, kt);
        CHUNK_BODY(vB, vA, kt + 1);
    }
#undef CHUNK_BODY
#undef DMA_TILE

#pragma unroll
    for (int rt = 0; rt < 2; ++rt) {
        if (li == 0) {
#pragma unroll
            for (int reg = 0; reg < 4; ++reg)
                rsP[(size_t)(ks * NH + h) * NN + row0 + rt * 16 + q * 4 + reg] = rsacc[rt][reg];
        }
        __hip_bfloat16* ap = accP + ((size_t)(ks * NH + h) * NN + row0 + rt * 16) * 64;
#pragma unroll
        for (int n = 0; n < 4; ++n)
#pragma unroll
            for (int reg = 0; reg < 4; ++reg)
                ap[(q * 4 + reg) * 64 + n * 16 + li] = __float2bfloat16(acc[rt][n][reg]);
    }
}

// ---------------- K2: combine k-split partials + mean heads + skip + LeakyReLU
__global__ __launch_bounds__(256) void combine_kernel(
    const __hip_bfloat16* __restrict__ accP, const float* __restrict__ rsP,
    float* __restrict__ out) {
    int idx = blockIdx.x * 256 + threadIdx.x;      // 262144
    int row = idx >> 6, f = idx & 63;
    float s = 0.f;
#pragma unroll 1
    for (int h = 0; h < NH; ++h) {
        float a = 0.f, r = 0.f;
#pragma unroll
        for (int k = 0; k < KS; ++k) {
            a += __bfloat162float(accP[((size_t)(k * NH + h) * NN + row) * 64 + f]);
            r += rsP[(size_t)(k * NH + h) * NN + row];
        }
        s += a / r;
    }
    float v = s * 0.125f + out[idx];               // out currently holds skipm
    out[idx] = fmaxf(v, 0.2f * v);
}

extern "C" void kernel_launch(void* const* d_in, const int* in_sizes, int n_in,
                              void* d_out, int out_size, void* d_ws, size_t ws_size,
                              hipStream_t stream) {
    (void)in_sizes; (void)n_in; (void)out_size; (void)ws_size;
    const float* x         = (const float*)d_in[0];   // [4096,128]
    const float* topology  = (const float*)d_in[1];   // [4096,4096]
    const float* proj      = (const float*)d_in[2];   // [8,128,64]
    const float* score_src = (const float*)d_in[3];   // [8,64]
    const float* score_dst = (const float*)d_in[4];   // [8,64]
    const float* skip_w    = (const float*)d_in[5];   // [512,128]
    float* out = (float*)d_out;                       // [4096,64]

    char* ws = (char*)d_ws;
    __hip_bfloat16* Vt = (__hip_bfloat16*)(ws + 1048576);     // 4 MB
    unsigned* EF  = (unsigned*)(ws + 5242880);                // 128 KB
    float2* C12   = (float2*)(ws + 5373952);                  // 256 KB
    u64* maskbits = (u64*)(ws + 5677056);                     // 2 MB
    float* rsP    = (float*)(ws + 7774208);                   // 512 KB
    __hip_bfloat16* accP = (__hip_bfloat16*)(ws + 8298496);   // 16 MB (end ~24.3 MB)
    float* skipm = out;   // skip GEMM lives in d_out; combine consumes & overwrites

    prep_kernel<<<2176, 256, 0, stream>>>(x, topology, proj, score_src, score_dst,
                                          skip_w, skipm, EF, C12, Vt, maskbits);
    attn_kernel<<<1024, 256, 0, stream>>>(maskbits, Vt, EF, C12, accP, rsP);
    combine_kernel<<<1024, 256, 0, stream>>>(accP, rsP, out);
}